// Round 6
// baseline (600.333 us; speedup 1.0000x reference)
//
#include <hip/hip_runtime.h>

// NodeGNN: h = lrelu(lrelu(x@W1+b1)@W2+b2); 2x GCNConv(16->16) over E=6.4M edges
// + self loops with symmetric norm; out = sum(h@pw+pb, -1). Returns (out[N], h[N,16]).
//
// R6: gather made L2-resident. R5 lesson: fetch granule is a 64B line, so halving
// row bytes didn't halve traffic — miss rate is the lever (6.4MB rows vs 4MiB/XCD
// L2 thrashed: 282MB fetch). Now rows live in two separate 8-feature bf16 arrays
// (3.2MB each, dinv[src] pre-folded in) and each conv runs two gather passes whose
// working set fits L2. agg split likewise for full-line writes.

#define NEG 0.01f
#define SHIFT 9                 // 512 nodes per bucket
#define BNODES (1 << SHIFT)
#define BMAX 512                // max buckets (N <= 262144)
#define PCHUNK 8192             // edges per partition block

typedef __attribute__((ext_vector_type(8))) short short8;
typedef __attribute__((ext_vector_type(4))) float floatx4;
typedef __attribute__((ext_vector_type(4))) unsigned short us4;
typedef __attribute__((ext_vector_type(8))) unsigned short us8;

__device__ __forceinline__ float lrelu(float v) { return v >= 0.0f ? v : NEG * v; }

__device__ __forceinline__ unsigned short f2bf(float f) {
    unsigned int u = __float_as_uint(f);
    u += 0x7fffu + ((u >> 16) & 1u);          // round-to-nearest-even
    return (unsigned short)(u >> 16);
}
__device__ __forceinline__ float bflo(unsigned int u) { return __uint_as_float(u << 16); }
__device__ __forceinline__ float bfhi(unsigned int u) { return __uint_as_float(u & 0xffff0000u); }

// ---------------------------------------------------------------------------
// K-prep: bf16-transposed weights. W1T[n][k] = bf16(W1[k][n]) (256x128),
// W2T[c][k] = bf16(W2[k][c]) (16x256).
// ---------------------------------------------------------------------------
__global__ void prep_kernel(const float* __restrict__ W1, const float* __restrict__ W2,
                            unsigned short* __restrict__ W1T, unsigned short* __restrict__ W2T)
{
    const int idx = blockIdx.x * 256 + threadIdx.x;
    const int stride = gridDim.x * 256;
    for (int i = idx; i < 256 * 128; i += stride) {
        int n = i >> 7, k = i & 127;
        W1T[i] = f2bf(W1[k * 256 + n]);
    }
    for (int i = idx; i < 16 * 256; i += stride) {
        int c = i >> 8, k = i & 255;
        W2T[i] = f2bf(W2[k * 16 + c]);
    }
}

// ---------------------------------------------------------------------------
// K1: MFMA MLP. Block = 256 threads (4 waves), 64 nodes/block. (unchanged R3)
// ---------------------------------------------------------------------------
__global__ __launch_bounds__(256, 3) void mlp_mfma(
    const float* __restrict__ x, const unsigned short* __restrict__ W1T,
    const float* __restrict__ b1, const unsigned short* __restrict__ W2T,
    const float* __restrict__ b2, float* __restrict__ h, int N)
{
    __shared__ unsigned short xbf[64][136];   // 17.0 KB
    __shared__ unsigned short h1s[64][264];   // 33.8 KB

    const int tid  = threadIdx.x;
    const int n0   = blockIdx.x * 64;
    const int lane = tid & 63;
    const int lr   = lane & 15;
    const int quad = lane >> 4;
    const int wv   = tid >> 6;

    {
        const float4* xg = (const float4*)(x + (size_t)n0 * 128);
#pragma unroll
        for (int i = 0; i < 8; ++i) {
            int f = tid + 256 * i;
            float4 v = xg[f];
            int r = f >> 5, c = (f & 31) * 4;
            us4 p;
            p.x = f2bf(v.x); p.y = f2bf(v.y); p.z = f2bf(v.z); p.w = f2bf(v.w);
            *(us4*)&xbf[r][c] = p;
        }
    }
    __syncthreads();

    short8 af[4][4];
#pragma unroll
    for (int m = 0; m < 4; ++m)
#pragma unroll
        for (int kt = 0; kt < 4; ++kt)
            af[m][kt] = *(const short8*)&xbf[m * 16 + lr][kt * 32 + quad * 8];

    floatx4 acc[4][4];
#pragma unroll
    for (int n = 0; n < 4; ++n)
#pragma unroll
        for (int m = 0; m < 4; ++m)
            acc[n][m] = (floatx4){0.f, 0.f, 0.f, 0.f};

    const int nbase = wv * 64;
#pragma unroll
    for (int n = 0; n < 4; ++n) {
        const unsigned short* bp = &W1T[(size_t)(nbase + n * 16 + lr) * 128 + quad * 8];
        short8 bfr[4];
#pragma unroll
        for (int kt = 0; kt < 4; ++kt) bfr[kt] = *(const short8*)(bp + kt * 32);
#pragma unroll
        for (int kt = 0; kt < 4; ++kt)
#pragma unroll
            for (int m = 0; m < 4; ++m)
                acc[n][m] = __builtin_amdgcn_mfma_f32_16x16x32_bf16(
                    af[m][kt], bfr[kt], acc[n][m], 0, 0, 0);
    }

#pragma unroll
    for (int n = 0; n < 4; ++n) {
        float bc = b1[nbase + n * 16 + lr];
#pragma unroll
        for (int m = 0; m < 4; ++m)
#pragma unroll
            for (int reg = 0; reg < 4; ++reg) {
                float v = lrelu(acc[n][m][reg] + bc);
                h1s[m * 16 + quad * 4 + reg][nbase + n * 16 + lr] = f2bf(v);
            }
    }
    __syncthreads();

    floatx4 acc2 = (floatx4){0.f, 0.f, 0.f, 0.f};
#pragma unroll
    for (int kt = 0; kt < 8; ++kt) {
        short8 a2 = *(const short8*)&h1s[wv * 16 + lr][kt * 32 + quad * 8];
        short8 b2f = *(const short8*)&W2T[lr * 256 + kt * 32 + quad * 8];
        acc2 = __builtin_amdgcn_mfma_f32_16x16x32_bf16(a2, b2f, acc2, 0, 0, 0);
    }
    float bb = b2[lr];
#pragma unroll
    for (int reg = 0; reg < 4; ++reg) {
        int r = n0 + wv * 16 + quad * 4 + reg;
        h[(size_t)r * 16 + lr] = lrelu(acc2[reg] + bb);
    }
}

// ---------------------------------------------------------------------------
// K0: zero the global bucket counters
// ---------------------------------------------------------------------------
__global__ void zero_kernel(int* __restrict__ bcnt)
{
    bcnt[threadIdx.x] = 0;
}

// ---------------------------------------------------------------------------
// K2: per-bucket edge histogram (LDS-aggregated)
// ---------------------------------------------------------------------------
__global__ __launch_bounds__(256) void bucket_count(
    const int* __restrict__ eidx, int* __restrict__ bcnt, int E, int N, int B)
{
    __shared__ int hist[BMAX];
    const int t = threadIdx.x;
    for (int b = t; b < B; b += 256) hist[b] = 0;
    __syncthreads();

    const int stride = gridDim.x * 256;
    for (int e = blockIdx.x * 256 + t; e < E; e += stride) {
        int d = eidx[E + e];
        d = min(max(d, 0), N - 1);
        atomicAdd(&hist[d >> SHIFT], 1);
    }
    __syncthreads();
    for (int b = t; b < B; b += 256) {
        int c = hist[b];
        if (c) atomicAdd(&bcnt[b], c);
    }
}

// ---------------------------------------------------------------------------
// K3: single-block exclusive scan over bucket counts
// ---------------------------------------------------------------------------
__global__ __launch_bounds__(512) void scan_kernel(
    const int* __restrict__ bcnt, int* __restrict__ bbase, int* __restrict__ gcur, int B)
{
    __shared__ int s[BMAX];
    const int t = threadIdx.x;        // 512 threads
    int c = (t < B) ? bcnt[t] : 0;
    s[t] = c;
    __syncthreads();
#pragma unroll
    for (int off = 1; off < BMAX; off <<= 1) {
        int v = s[t];
        int u = (t >= off) ? s[t - off] : 0;
        __syncthreads();
        s[t] = v + u;
        __syncthreads();
    }
    if (t < B) {
        int excl = s[t] - c;
        bbase[t] = excl;
        gcur[t]  = excl;
    }
    if (t == 0) bbase[B] = s[BMAX - 1];
}

// ---------------------------------------------------------------------------
// K4: partition via block-level LDS counting sort + coalesced run flush.
// ---------------------------------------------------------------------------
__global__ __launch_bounds__(512) void partition_kernel(
    const int* __restrict__ eidx, int* __restrict__ gcur, int* __restrict__ pairs,
    int E, int N, int B)
{
    __shared__ int hist[BMAX];        // count -> cursor
    __shared__ int offx[BMAX + 1];    // exclusive local offsets (kept intact)
    __shared__ int basec[BMAX];       // global run base for this block
    __shared__ int sorted[PCHUNK];    // 32KB; doubles as scan scratch
    const int t  = threadIdx.x;
    const int e0 = blockIdx.x * PCHUNK;
    const int elim = min(PCHUNK, E - e0);

    hist[t] = 0;
    __syncthreads();
    for (int i = t; i < elim; i += 512) {
        int d = eidx[E + e0 + i];
        d = min(max(d, 0), N - 1);
        atomicAdd(&hist[d >> SHIFT], 1);
    }
    __syncthreads();

    int c = hist[t];
    sorted[t] = c;
    __syncthreads();
#pragma unroll
    for (int o = 1; o < BMAX; o <<= 1) {
        int v = sorted[t];
        int u = (t >= o) ? sorted[t - o] : 0;
        __syncthreads();
        sorted[t] = v + u;
        __syncthreads();
    }
    const int excl = sorted[t] - c;
    offx[t] = excl;
    if (t == 0) offx[BMAX] = elim;
    basec[t] = (t < B && c) ? atomicAdd(&gcur[t], c) : 0;
    hist[t] = excl;                   // becomes local cursor
    __syncthreads();

    for (int i = t; i < elim; i += 512) {
        int s = eidx[e0 + i];
        int d = eidx[E + e0 + i];
        s = min(max(s, 0), N - 1);
        d = min(max(d, 0), N - 1);
        int b = d >> SHIFT;
        int p = atomicAdd(&hist[b], 1);
        sorted[p] = (s << SHIFT) | (d & (BNODES - 1));
    }
    __syncthreads();

    for (int slot = t; slot < elim; slot += 512) {
        int v = sorted[slot];
        int l = 0, r = BMAX - 1;
#pragma unroll
        for (int it = 0; it < 9; ++it) {
            int m = (l + r + 1) >> 1;
            if (offx[m] <= slot) l = m; else r = m - 1;
        }
        pairs[basec[l] + (slot - offx[l])] = v;
    }
}

// ---------------------------------------------------------------------------
// K5: per-bucket counting sort -> csr, plus row_start/cnt/dinv
// ---------------------------------------------------------------------------
__global__ __launch_bounds__(512) void build_csr(
    const int* __restrict__ pairs, const int* __restrict__ bbase,
    int* __restrict__ row_start, int* __restrict__ cnt_out, float* __restrict__ dinv,
    int* __restrict__ csr, int N)
{
    __shared__ int cnt[BNODES];
    __shared__ int off[BNODES];
    const int b = blockIdx.x, t = threadIdx.x;   // 512 threads
    const int node0 = b << SHIFT;
    const int lo = bbase[b], hi = bbase[b + 1];

    cnt[t] = 0;
    __syncthreads();
    for (int e = lo + t; e < hi; e += 512)
        atomicAdd(&cnt[pairs[e] & (BNODES - 1)], 1);
    __syncthreads();

    int c = cnt[t];
    off[t] = c;
    __syncthreads();
#pragma unroll
    for (int o = 1; o < BNODES; o <<= 1) {
        int v = off[t];
        int u = (t >= o) ? off[t - o] : 0;
        __syncthreads();
        off[t] = v + u;
        __syncthreads();
    }
    const int excl = off[t] - c;
    const int node = node0 + t;
    if (node < N) {
        row_start[node] = lo + excl;
        cnt_out[node]   = c;
        dinv[node]      = rsqrtf((float)(c + 1));
    }
    cnt[t] = lo + excl;              // reuse as cursor
    __syncthreads();
    for (int e = lo + t; e < hi; e += 512) {
        int v = pairs[e];
        int p = atomicAdd(&cnt[v & (BNODES - 1)], 1);
        csr[p] = v >> SHIFT;
    }
}

// ---------------------------------------------------------------------------
// K6: hw halves = ((optionally lrelu(in + bias_prev)) @ W[16x16]) * dinv -> bf16.
// in row i = {in0 + i*stride (feat 0..7), in1 + i*stride (feat 8..15)}.
// ---------------------------------------------------------------------------
__global__ void hw_kernel(const float* __restrict__ in0, const float* __restrict__ in1,
                          int stride, const float* __restrict__ W,
                          const float* __restrict__ bias, const float* __restrict__ dinv,
                          unsigned short* __restrict__ hws0, unsigned short* __restrict__ hws1,
                          int N, int apply)
{
    int i = blockIdx.x * 256 + threadIdx.x;
    if (i >= N) return;
    float4 r0 = *(const float4*)(in0 + (size_t)i * stride);
    float4 r1 = *(const float4*)(in0 + (size_t)i * stride + 4);
    float4 r2 = *(const float4*)(in1 + (size_t)i * stride);
    float4 r3 = *(const float4*)(in1 + (size_t)i * stride + 4);
    float v[16] = {r0.x, r0.y, r0.z, r0.w, r1.x, r1.y, r1.z, r1.w,
                   r2.x, r2.y, r2.z, r2.w, r3.x, r3.y, r3.z, r3.w};
    if (apply) {
#pragma unroll
        for (int c = 0; c < 16; ++c) v[c] = lrelu(v[c] + bias[c]);
    }
    float o[16];
#pragma unroll
    for (int c = 0; c < 16; ++c) o[c] = 0.0f;
#pragma unroll
    for (int k = 0; k < 16; ++k) {
        float vk = v[k];
#pragma unroll
        for (int c = 0; c < 16; ++c) o[c] += vk * W[k * 16 + c];
    }
    float di = dinv[i];
    us8 lo, hi;
#pragma unroll
    for (int c = 0; c < 8; ++c) { lo[c] = f2bf(o[c] * di); hi[c] = f2bf(o[c + 8] * di); }
    *(us8*)(hws0 + (size_t)i * 8) = lo;
    *(us8*)(hws1 + (size_t)i * 8) = hi;
}

// ---------------------------------------------------------------------------
// K7: gather over one 8-feature half (3.2MB, L2-resident). 4 lanes/node,
// lane cp owns features 2cp,2cp+1. dinv[src] pre-folded into rows.
// aggh[d] = dinv_d * (rows_d + sum_src rows_src)
// ---------------------------------------------------------------------------
__global__ __launch_bounds__(256) void gather_half(
    const unsigned int* __restrict__ rows, const float* __restrict__ dinv,
    const int* __restrict__ csr, const int* __restrict__ row_start,
    const int* __restrict__ cnt, float* __restrict__ aggh, int N)
{
    int t    = blockIdx.x * 256 + threadIdx.x;
    int node = t >> 2;
    int cp   = t & 3;
    if (node >= N) return;

    int   s0 = row_start[node];
    int   n  = cnt[node];
    float di = dinv[node];
    unsigned int self = rows[(size_t)node * 4 + cp];
    float a0 = bflo(self), a1 = bfhi(self);

    int j = 0;
    for (; j + 4 <= n; j += 4) {
        int sa = csr[s0 + j + 0]; int sb = csr[s0 + j + 1];
        int sc = csr[s0 + j + 2]; int sd = csr[s0 + j + 3];
        unsigned int va = rows[(size_t)sa * 4 + cp];
        unsigned int vb = rows[(size_t)sb * 4 + cp];
        unsigned int vc = rows[(size_t)sc * 4 + cp];
        unsigned int vd = rows[(size_t)sd * 4 + cp];
        a0 += bflo(va); a1 += bfhi(va);
        a0 += bflo(vb); a1 += bfhi(vb);
        a0 += bflo(vc); a1 += bfhi(vc);
        a0 += bflo(vd); a1 += bfhi(vd);
    }
    for (; j < n; ++j) {
        unsigned int v = rows[(size_t)csr[s0 + j] * 4 + cp];
        a0 += bflo(v); a1 += bfhi(v);
    }
    *(float2*)&aggh[(size_t)node * 8 + cp * 2] = make_float2(a0 * di, a1 * di);
}

// ---------------------------------------------------------------------------
// K8: final head from agg halves. h = lrelu(agg + cb1);
// out = h . (pw[:,0]+pw[:,1]) + pb0+pb1
// ---------------------------------------------------------------------------
__global__ void final_kernel(const float* __restrict__ agg0, const float* __restrict__ agg1,
                             const float* __restrict__ cb1,
                             const float* __restrict__ pw, const float* __restrict__ pb,
                             float* __restrict__ out, float* __restrict__ hout, int N)
{
    int i = blockIdx.x * 256 + threadIdx.x;
    if (i >= N) return;
    float4 r0 = *(const float4*)(agg0 + (size_t)i * 8);
    float4 r1 = *(const float4*)(agg0 + (size_t)i * 8 + 4);
    float4 r2 = *(const float4*)(agg1 + (size_t)i * 8);
    float4 r3 = *(const float4*)(agg1 + (size_t)i * 8 + 4);
    float v[16] = {r0.x, r0.y, r0.z, r0.w, r1.x, r1.y, r1.z, r1.w,
                   r2.x, r2.y, r2.z, r2.w, r3.x, r3.y, r3.z, r3.w};
    float s = pb[0] + pb[1];
#pragma unroll
    for (int c = 0; c < 16; ++c) {
        v[c] = lrelu(v[c] + cb1[c]);
        s += v[c] * (pw[c * 2] + pw[c * 2 + 1]);
    }
    out[i] = s;
    float4* hr = (float4*)(hout + (size_t)i * 16);
    hr[0] = make_float4(v[0],  v[1],  v[2],  v[3]);
    hr[1] = make_float4(v[4],  v[5],  v[6],  v[7]);
    hr[2] = make_float4(v[8],  v[9],  v[10], v[11]);
    hr[3] = make_float4(v[12], v[13], v[14], v[15]);
}

// ---------------------------------------------------------------------------
extern "C" void kernel_launch(void* const* d_in, const int* in_sizes, int n_in,
                              void* d_out, int out_size, void* d_ws, size_t ws_size,
                              hipStream_t stream)
{
    const float* x   = (const float*)d_in[0];
    const float* W1  = (const float*)d_in[1];
    const float* b1  = (const float*)d_in[2];
    const float* W2  = (const float*)d_in[3];
    const float* b2  = (const float*)d_in[4];
    const float* cw0 = (const float*)d_in[5];
    const float* cb0 = (const float*)d_in[6];
    const float* cw1 = (const float*)d_in[7];
    const float* cb1 = (const float*)d_in[8];
    const float* pw  = (const float*)d_in[9];
    const float* pb  = (const float*)d_in[10];
    const int*   eidx = (const int*)d_in[11];

    const int N = in_sizes[0] / 128;
    const int E = in_sizes[11] / 2;
    const int B = (N + BNODES - 1) >> SHIFT;

    // workspace carve-out (~60 MB); X region timeline: pairs -> h -> agg halves
    char* w = (char*)d_ws;
    unsigned short* hws0 = (unsigned short*)w; w += (size_t)N * 8 * 2;  // 3.2MB
    unsigned short* hws1 = (unsigned short*)w; w += (size_t)N * 8 * 2;  // 3.2MB
    float* dinv    = (float*)w; w += (size_t)N * 4;
    int*   cnt     = (int*)w;   w += (size_t)N * 4;
    int*   row_st  = (int*)w;   w += (size_t)N * 4;
    int*   csr     = (int*)w;   w += (size_t)E * 4;
    char*  X       = w;         w += (size_t)E * 4;
    int*   bcnt    = (int*)w;   w += BMAX * 4;
    int*   bbase   = (int*)w;   w += (BMAX + 4) * 4;   // +4 keeps 16B alignment below
    int*   gcur    = (int*)w;   w += BMAX * 4;
    unsigned short* W1T = (unsigned short*)w; w += 256 * 128 * 2;  // 16B-aligned
    unsigned short* W2T = (unsigned short*)w; w += 16 * 256 * 2;

    int*   pairs = (int*)X;                      // live: partition -> build_csr
    float* h     = (float*)X;                    // live: mlp -> hw1
    float* agg0  = (float*)X;                    // live: gather -> hw2/final
    float* agg1  = (float*)(X + (size_t)N * 8 * 4);

    float* out  = (float*)d_out;
    float* hout = out + N;

    const int nb_n  = (N + 255) / 256;
    const int nb_g  = (N * 4 + 255) / 256;
    const int nb_p  = (E + PCHUNK - 1) / PCHUNK;

    zero_kernel<<<1, BMAX, 0, stream>>>(bcnt);
    bucket_count<<<1024, 256, 0, stream>>>(eidx, bcnt, E, N, B);
    scan_kernel<<<1, BMAX, 0, stream>>>(bcnt, bbase, gcur, B);
    partition_kernel<<<nb_p, 512, 0, stream>>>(eidx, gcur, pairs, E, N, B);
    build_csr<<<B, 512, 0, stream>>>(pairs, bbase, row_st, cnt, dinv, csr, N);  // pairs dead
    prep_kernel<<<32, 256, 0, stream>>>(W1, W2, W1T, W2T);
    mlp_mfma<<<N / 64, 256, 0, stream>>>(x, W1T, b1, W2T, b2, h, N);
    hw_kernel<<<nb_n, 256, 0, stream>>>(h, h + 8, 16, cw0, nullptr, dinv, hws0, hws1, N, 0); // h dead
    gather_half<<<nb_g, 256, 0, stream>>>((const unsigned int*)hws0, dinv, csr, row_st, cnt, agg0, N);
    gather_half<<<nb_g, 256, 0, stream>>>((const unsigned int*)hws1, dinv, csr, row_st, cnt, agg1, N);
    hw_kernel<<<nb_n, 256, 0, stream>>>(agg0, agg1, 8, cw1, cb0, dinv, hws0, hws1, N, 1);
    gather_half<<<nb_g, 256, 0, stream>>>((const unsigned int*)hws0, dinv, csr, row_st, cnt, agg0, N);
    gather_half<<<nb_g, 256, 0, stream>>>((const unsigned int*)hws1, dinv, csr, row_st, cnt, agg1, N);
    final_kernel<<<nb_n, 256, 0, stream>>>(agg0, agg1, cb1, pw, pb, out, hout, N);
}